// Round 2
// 92.867 us; speedup vs baseline: 1.0201x; 1.0201x over previous
//
#include <hip/hip_runtime.h>
#include <math.h>

#define WG 256

// Native vector type for nontemporal stores (builtin rejects HIP_vector_type).
typedef float v4f __attribute__((ext_vector_type(4)));

// Fast acos: Hastings-style minimax, |err| < 7e-5 rad, branch-light.
// acos(x) = sqrt(1-x) * p(x) for x in [0,1]; acos(-x) = pi - acos(x).
__device__ __forceinline__ float fast_acosf(float x) {
    float ax = __builtin_fabsf(x);
    float p = __builtin_fmaf(ax, -0.0187293f, 0.0742610f);
    p = __builtin_fmaf(ax, p, -0.2121144f);
    p = __builtin_fmaf(ax, p, 1.5707288f);
    float t = __builtin_amdgcn_sqrtf(1.0f - ax) * p;
    return (x >= 0.0f) ? t : (3.14159265358979324f - t);
}

// Smith's trigonometric closed form for symmetric 3x3 eigenvalues, ascending.
// Transcendentals: fast_acosf + hardware v_sin/v_cos (input in revolutions;
// phi/3 in [0, pi/3] -> rev in [0, 1/6], no range reduction needed).
__device__ __forceinline__ void eig3_sym(float a00, float a11, float a22,
                                         float a01, float a02, float a12,
                                         float& e0, float& e1, float& e2) {
    const float third = 1.0f / 3.0f;
    float p1 = a01 * a01 + a02 * a02 + a12 * a12;
    float q  = (a00 + a11 + a22) * third;
    float b00 = a00 - q, b11 = a11 - q, b22 = a22 - q;
    float p2 = b00 * b00 + b11 * b11 + b22 * b22 + 2.0f * p1;
    float p2_6 = p2 * (1.0f / 6.0f);
    // p = sqrt(p2/6), invp = 1/p — via a single rsqrt, no divide, no sqrt.
    float invp = 0.0f, p = 0.0f;
    if (p2_6 > 0.0f) {
        invp = rsqrtf(p2_6);
        p = p2_6 * invp;
    }
    // det(A - qI) for the symmetrized matrix
    float det = b00 * (b11 * b22 - a12 * a12)
              - a01 * (a01 * b22 - a12 * a02)
              + a02 * (a01 * a12 - b11 * a02);
    float r = 0.5f * det * invp * invp * invp;
    r = fminf(1.0f, fmaxf(-1.0f, r));
    // rev = acos(r) / 3 / (2*pi) = acos(r) * (1/(6*pi))
    float rev = fast_acosf(r) * 0.05305164769729845f;
    float s = __builtin_amdgcn_sinf(rev);   // v_sin_f32, revolutions
    float c = __builtin_amdgcn_cosf(rev);   // v_cos_f32, revolutions
    float twop = 2.0f * p;
    float emax = q + twop * c;                                        // cos(phi) >= 0.5
    float emin = q + twop * (-0.5f * c - 0.86602540378443864676f * s); // cos(phi+2pi/3)
    float emid = 3.0f * q - emax - emin;
    e0 = emin; e1 = emid; e2 = emax;
}

// One thread handles 4 consecutive voxels: float4 load per channel plane,
// float4 store per eigenvalue plane. All accesses 16B-aligned & coalesced.
__global__ __launch_bounds__(WG) void eigvals_kernel(const float* __restrict__ X,
                                                     float* __restrict__ out,
                                                     int nv /* n/4 */,
                                                     long long n) {
    int tid = blockIdx.x * WG + threadIdx.x;
    int total = 2 * nv;  // b = 2
    if (tid >= total) return;
    int b = (tid >= nv) ? 1 : 0;  // avoid integer division
    int j = tid - b * nv;

    const float* src = X + (long long)b * 9 * n + 4LL * j;
    float4 m[9];
#pragma unroll
    for (int c = 0; c < 9; ++c)
        m[c] = *(const float4*)(src + (long long)c * n);

    v4f o0, o1, o2;
    float* p0 = (float*)&o0;
    float* p1 = (float*)&o1;
    float* p2 = (float*)&o2;
#pragma unroll
    for (int k = 0; k < 4; ++k) {
        float a00 = ((const float*)&m[0])[k];
        float a01 = ((const float*)&m[1])[k];
        float a02 = ((const float*)&m[2])[k];
        float a10 = ((const float*)&m[3])[k];
        float a11 = ((const float*)&m[4])[k];
        float a12 = ((const float*)&m[5])[k];
        float a20 = ((const float*)&m[6])[k];
        float a21 = ((const float*)&m[7])[k];
        float a22 = ((const float*)&m[8])[k];
        // symmetrize: 0.5 * (M + M^T)
        float s01 = 0.5f * (a01 + a10);
        float s02 = 0.5f * (a02 + a20);
        float s12 = 0.5f * (a12 + a21);
        eig3_sym(a00, a11, a22, s01, s02, s12, p0[k], p1[k], p2[k]);
    }

    // Output is never re-read: nontemporal stores, don't pollute L2/L3.
    float* dst = out + (long long)b * 3 * n + 4LL * j;
    __builtin_nontemporal_store(o0, (v4f*)(dst));
    __builtin_nontemporal_store(o1, (v4f*)(dst + n));
    __builtin_nontemporal_store(o2, (v4f*)(dst + 2 * n));
}

extern "C" void kernel_launch(void* const* d_in, const int* in_sizes, int n_in,
                              void* d_out, int out_size, void* d_ws, size_t ws_size,
                              hipStream_t stream) {
    const float* X = (const float*)d_in[0];
    float* out = (float*)d_out;
    // in_sizes[0] = b(=2) * 9 * n  ->  n = in_sizes[0] / 18
    long long n = (long long)in_sizes[0] / 18;
    int nv = (int)(n / 4);        // n = 96^3 is divisible by 4
    int total = 2 * nv;
    int blocks = (total + WG - 1) / WG;
    eigvals_kernel<<<blocks, WG, 0, stream>>>(X, out, nv, n);
}